// Round 2
// baseline (240.453 us; speedup 1.0000x reference)
//
#include <hip/hip_runtime.h>
#include <hip/hip_bf16.h>
#include <hip/hip_cooperative_groups.h>
#include <cmath>

namespace cg = cooperative_groups;

constexpr int N_NODES = 10000;
constexpr int D_IN = 128;   // GraphConv dim
constexpr int H_DIM = 256;  // MLP hidden

// Bucket geometry: bucket = dst>>5 (32 nodes/bucket), 313 buckets.
constexpr int NB = 313;
constexpr int BCAP = 3072;      // avg 2045 edges/bucket, sigma ~45 -> 22-sigma margin
constexpr int EPB_A = 2048;     // legacy fallback: edges per binsort block (256 thr x 8)

// Mega (cooperative) geometry: 157 blocks x 512 thr, 2 buckets (64 nodes) each.
constexpr int GRID = 157;       // (N_NODES+63)/64
constexpr int THREADS = 512;
constexpr int EPB = 4096;       // binsort edges/block: 157*4096 = 643072 >= E

typedef unsigned short u16;
typedef short bf16x8 __attribute__((ext_vector_type(8)));  // 8 bf16 = 4 VGPRs
typedef float f32x4 __attribute__((ext_vector_type(4)));

__device__ inline u16 f2bf(float f) {
    return __builtin_bit_cast(u16, __float2bfloat16(f));  // RNE hw cvt
}
__device__ inline float bf2f(u16 u) {
    unsigned int v = (unsigned int)u << 16;
    return __builtin_bit_cast(float, v);
}

// ===========================================================================
// MEGA: single cooperative kernel.
//   Phase A (all 157 blocks): grid-strided x fp32->bf16 cast; weight casts
//     (Wcat=[W_rel|W_root], W1b, W2b); per-block binsort slice (4096 edges,
//     LDS hist + one global cursor reservation per (block,bucket)).
//   grid.sync (with device-scope fences for cross-XCD visibility).
//   Phase B (per block = buckets 2b,2b+1 = 64 nodes): LDS counting-sort of
//     both buckets, gather straight into the MFMA A-tile (bufA cols 0..127),
//     x rows into cols 128..255, then the validated 3-phase MFMA MLP + head.
// LDS 122.6 KB -> 1 block/CU; 157 blocks co-resident (<=256 CUs). All
// compute bodies verbatim from the R8-validated 4-kernel pipeline.
// ===========================================================================
__global__ __launch_bounds__(THREADS)
void mega(const float* __restrict__ x, const int* __restrict__ ei,
          const float* __restrict__ W_rel, const float* __restrict__ W_root,
          const float* __restrict__ W1, const float* __restrict__ W2,
          const float* __restrict__ b_rel, const float* __restrict__ b1,
          const float* __restrict__ b2, const float* __restrict__ W3,
          const float* __restrict__ b3,
          u16* __restrict__ x_bf, u16* __restrict__ Wcat,
          u16* __restrict__ W1b, u16* __restrict__ W2b,
          int* __restrict__ gcnt, int* __restrict__ buckets,
          float* __restrict__ out, int E, int M)
{
    __shared__ alignas(16) u16 bufA[64 * 264];   // 33.8 KB: [agg|x], later h1
    __shared__ alignas(16) u16 bufH0[64 * 136];  // 17.4 KB
    union alignas(16) Ovl {
        struct { int lcnt[NB]; int gbase[NB]; } h;            // phase A binsort
        struct { int edges[2][BCAP]; u16 ssrc[2][BCAP]; } s;  // phase B sort
        u16 wbuf[34816];                                      // weight tiles
    };
    __shared__ Ovl ovl;                          // 69.6 KB
    __shared__ int deg[2][32], cur[2][32], sbeg[2][32];
    __shared__ float part[64][4];

    const int t = threadIdx.x, blk = blockIdx.x;
    const int w = t >> 6, lane = t & 63;
    const int wm = w >> 2, wn = w & 3;
    const int l16 = lane & 15, q = lane >> 4;
    const int r0 = blk * 64;

    // ================= Phase A =================
    {
        const int tid = blk * THREADS + t;
        // x fp32 -> bf16 dense (grid-strided; 320000 float4 chunks)
        for (int idx = tid; idx < N_NODES * 32; idx += GRID * THREADS) {
            int row = idx >> 5, c = (idx & 31) * 4;
            float4 v = *reinterpret_cast<const float4*>(x + (size_t)row * D_IN + c);
            ushort4 o;
            o.x = f2bf(v.x); o.y = f2bf(v.y); o.z = f2bf(v.z); o.w = f2bf(v.w);
            *reinterpret_cast<ushort4*>(x_bf + (size_t)row * D_IN + c) = o;
        }
        // weight casts (32768 float4 chunks; first 64 blocks' threads)
        if (tid < 32768) {
            int idx4 = tid * 4;
            const float* src;
            u16* dst;
            if (idx4 < 32768) {            // Wcat = [W_rel|W_root]
                int n = idx4 >> 8, k = idx4 & 255;
                src = (k < 128) ? W_rel + n * 128 + k : W_root + n * 128 + (k - 128);
                dst = Wcat + idx4;
            } else if (idx4 < 65536) {     // W1
                src = W1 + (idx4 - 32768);
                dst = W1b + (idx4 - 32768);
            } else {                       // W2
                src = W2 + (idx4 - 65536);
                dst = W2b + (idx4 - 65536);
            }
            float4 v = *reinterpret_cast<const float4*>(src);
            ushort4 o;
            o.x = f2bf(v.x); o.y = f2bf(v.y); o.z = f2bf(v.z); o.w = f2bf(v.w);
            *reinterpret_cast<ushort4*>(dst) = o;
        }
        // binsort slice: edges [blk*EPB, blk*EPB+4096)
        for (int i = t; i < NB; i += THREADS) ovl.h.lcnt[i] = 0;
        __syncthreads();
        const int e0 = blk * EPB + t;
        int packed[8], lpos[8], bb[8];
#pragma unroll
        for (int j = 0; j < 8; ++j) {
            int e = e0 + j * THREADS;
            if (e < E) {
                int s = ei[e], d = ei[E + e];
                int b = d >> 5;
                bb[j] = b;
                packed[j] = ((d & 31) << 16) | s;
                lpos[j] = atomicAdd(&ovl.h.lcnt[b], 1);
            } else bb[j] = -1;
        }
        __syncthreads();
        for (int i = t; i < NB; i += THREADS)
            ovl.h.gbase[i] = atomicAdd(&gcnt[i], ovl.h.lcnt[i]);
        __syncthreads();
#pragma unroll
        for (int j = 0; j < 8; ++j)
            if (bb[j] >= 0)
                buckets[bb[j] * BCAP + ovl.h.gbase[bb[j]] + lpos[j]] = packed[j];
    }

    // ---- grid-wide barrier; fences for cross-XCD L2 visibility ----
    __threadfence();
    cg::this_grid().sync();
    __threadfence();

    // ================= Phase B =================
    int cnt[2];
#pragma unroll
    for (int k = 0; k < 2; ++k) {
        int bk = blk * 2 + k;
        int c = (bk < NB) ? gcnt[bk] : 0;   // block 156's 2nd bucket: none
        cnt[k] = c > BCAP ? BCAP : c;
    }
    if (t < 64) deg[t >> 5][t & 31] = 0;
    __syncthreads();

    // stage self x rows -> bufA cols 128..255
    for (int idx = t; idx < 64 * 16; idx += THREADS) {
        int row = idx >> 4, kc = (idx & 15) * 8;
        int gr = r0 + row; if (gr >= M) gr = M - 1;
        bf16x8 vx = *reinterpret_cast<const bf16x8*>(x_bf + (size_t)gr * D_IN + kc);
        *reinterpret_cast<bf16x8*>(&bufA[row * 264 + 128 + kc]) = vx;
    }
    // load bucket edges + per-node hist
#pragma unroll
    for (int k = 0; k < 2; ++k) {
        int bk = blk * 2 + k;
        for (int i = t; i < cnt[k]; i += THREADS) {
            int p = buckets[bk * BCAP + i];
            ovl.s.edges[k][i] = p;
            atomicAdd(&deg[k][p >> 16], 1);
        }
    }
    __syncthreads();
    if (t < 64) {   // two 32-wide exclusive scans (segmented shfl, width 32)
        int k = t >> 5, tl = t & 31;
        int d = deg[k][tl], incl = d;
#pragma unroll
        for (int off = 1; off < 32; off <<= 1) {
            int o = __shfl_up(incl, off, 32);
            if (tl >= off) incl += o;
        }
        cur[k][tl] = incl - d;
        sbeg[k][tl] = incl - d;
    }
    __syncthreads();
#pragma unroll
    for (int k = 0; k < 2; ++k)
        for (int i = t; i < cnt[k]; i += THREADS) {
            int p = ovl.s.edges[k][i];
            int pos = atomicAdd(&cur[k][p >> 16], 1);
            ovl.s.ssrc[k][pos] = (u16)(p & 0xffff);
        }
    __syncthreads();

    // gather: wave w -> nodes w*4..w*4+3 of each bucket; agg -> bufA cols 0..127
    {
        const int c4 = (lane & 31) * 4;
        const int rh = lane >> 5;
#pragma unroll
        for (int k = 0; k < 2; ++k) {
            const u16* sp = ovl.s.ssrc[k];
#pragma unroll
            for (int j = 0; j < 4; ++j) {
                int ln = w * 4 + j;
                int beg = sbeg[k][ln], dg = deg[k][ln];
                int half = (dg + 1) >> 1;
                int i = beg + (rh ? half : 0);
                const int i1 = rh ? beg + dg : beg + half;
                float4 a0 = {0, 0, 0, 0}, a1 = {0, 0, 0, 0};
                float4 a2 = {0, 0, 0, 0}, a3 = {0, 0, 0, 0};
                for (; i + 4 <= i1; i += 4) {
                    int s0 = sp[i + 0], s1 = sp[i + 1];
                    int s2 = sp[i + 2], s3 = sp[i + 3];
                    ushort4 v0 = *reinterpret_cast<const ushort4*>(x_bf + (size_t)s0 * D_IN + c4);
                    ushort4 v1 = *reinterpret_cast<const ushort4*>(x_bf + (size_t)s1 * D_IN + c4);
                    ushort4 v2 = *reinterpret_cast<const ushort4*>(x_bf + (size_t)s2 * D_IN + c4);
                    ushort4 v3 = *reinterpret_cast<const ushort4*>(x_bf + (size_t)s3 * D_IN + c4);
                    a0.x += bf2f(v0.x); a0.y += bf2f(v0.y); a0.z += bf2f(v0.z); a0.w += bf2f(v0.w);
                    a1.x += bf2f(v1.x); a1.y += bf2f(v1.y); a1.z += bf2f(v1.z); a1.w += bf2f(v1.w);
                    a2.x += bf2f(v2.x); a2.y += bf2f(v2.y); a2.z += bf2f(v2.z); a2.w += bf2f(v2.w);
                    a3.x += bf2f(v3.x); a3.y += bf2f(v3.y); a3.z += bf2f(v3.z); a3.w += bf2f(v3.w);
                }
                for (; i < i1; ++i) {
                    int s = sp[i];
                    ushort4 v = *reinterpret_cast<const ushort4*>(x_bf + (size_t)s * D_IN + c4);
                    a0.x += bf2f(v.x); a0.y += bf2f(v.y); a0.z += bf2f(v.z); a0.w += bf2f(v.w);
                }
                a0.x += a1.x + a2.x + a3.x;
                a0.y += a1.y + a2.y + a3.y;
                a0.z += a1.z + a2.z + a3.z;
                a0.w += a1.w + a2.w + a3.w;
                a0.x += __shfl_xor(a0.x, 32);
                a0.y += __shfl_xor(a0.y, 32);
                a0.z += __shfl_xor(a0.z, 32);
                a0.w += __shfl_xor(a0.w, 32);
                if (rh == 0) {
                    int row = k * 32 + ln;
                    ushort4 o;
                    o.x = f2bf(a0.x); o.y = f2bf(a0.y); o.z = f2bf(a0.z); o.w = f2bf(a0.w);
                    *reinterpret_cast<ushort4*>(&bufA[row * 264 + c4]) = o;
                }
            }
        }
    }
    __syncthreads();   // sort scratch dead; bufA agg half complete

    // stage Wcat -> wbuf (overlays sort scratch)
    for (int idx = t; idx < 128 * 32; idx += THREADS) {
        int row = idx >> 5, kc = (idx & 31) * 8;
        bf16x8 v = *reinterpret_cast<const bf16x8*>(Wcat + (size_t)row * 256 + kc);
        *reinterpret_cast<bf16x8*>(&ovl.wbuf[row * 264 + kc]) = v;
    }
    __syncthreads();

    // Phase 1: h0[64][128] = A @ Wcat^T + b_rel
    {
        f32x4 acc[2][2] = {};
#pragma unroll
        for (int k0 = 0; k0 < 256; k0 += 32) {
            bf16x8 af[2];
#pragma unroll
            for (int i = 0; i < 2; ++i)
                af[i] = *reinterpret_cast<const bf16x8*>(
                    &bufA[(wm * 32 + i * 16 + l16) * 264 + k0 + q * 8]);
#pragma unroll
            for (int jj = 0; jj < 2; ++jj) {
                int col = wn * 32 + jj * 16 + l16;
                bf16x8 bv = *reinterpret_cast<const bf16x8*>(
                    &ovl.wbuf[col * 264 + k0 + q * 8]);
                acc[0][jj] = __builtin_amdgcn_mfma_f32_16x16x32_bf16(af[0], bv, acc[0][jj], 0, 0, 0);
                acc[1][jj] = __builtin_amdgcn_mfma_f32_16x16x32_bf16(af[1], bv, acc[1][jj], 0, 0, 0);
            }
        }
#pragma unroll
        for (int i = 0; i < 2; ++i)
#pragma unroll
            for (int jj = 0; jj < 2; ++jj) {
                int col = wn * 32 + jj * 16 + l16;
                float bb = b_rel[col];
#pragma unroll
                for (int r = 0; r < 4; ++r) {
                    int row = wm * 32 + i * 16 + q * 4 + r;
                    bufH0[row * 136 + col] = f2bf(acc[i][jj][r] + bb);
                }
            }
    }
    __syncthreads();   // wbuf reads + bufH0 writes complete

    // Stage W1b [256][128] (stride 136).
    for (int idx = t; idx < 256 * 16; idx += THREADS) {
        int row = idx >> 4, kc = (idx & 15) * 8;
        bf16x8 v = *reinterpret_cast<const bf16x8*>(W1b + (size_t)row * 128 + kc);
        *reinterpret_cast<bf16x8*>(&ovl.wbuf[row * 136 + kc]) = v;
    }
    __syncthreads();

    // Phase 2: h1[64][256] = relu(h0 @ W1^T + b1); h1 overlays bufA
    {
        f32x4 acc[2][4] = {};
#pragma unroll
        for (int k0 = 0; k0 < 128; k0 += 32) {
            bf16x8 af[2];
#pragma unroll
            for (int i = 0; i < 2; ++i)
                af[i] = *reinterpret_cast<const bf16x8*>(
                    &bufH0[(wm * 32 + i * 16 + l16) * 136 + k0 + q * 8]);
#pragma unroll
            for (int jj = 0; jj < 4; ++jj) {
                int col = wn * 64 + jj * 16 + l16;
                bf16x8 bv = *reinterpret_cast<const bf16x8*>(
                    &ovl.wbuf[col * 136 + k0 + q * 8]);
                acc[0][jj] = __builtin_amdgcn_mfma_f32_16x16x32_bf16(af[0], bv, acc[0][jj], 0, 0, 0);
                acc[1][jj] = __builtin_amdgcn_mfma_f32_16x16x32_bf16(af[1], bv, acc[1][jj], 0, 0, 0);
            }
        }
#pragma unroll
        for (int i = 0; i < 2; ++i)
#pragma unroll
            for (int jj = 0; jj < 4; ++jj) {
                int col = wn * 64 + jj * 16 + l16;
                float bb = b1[col];
#pragma unroll
                for (int r = 0; r < 4; ++r) {
                    int row = wm * 32 + i * 16 + q * 4 + r;
                    bufA[row * 264 + col] = f2bf(fmaxf(acc[i][jj][r] + bb, 0.f));
                }
            }
    }

    // Phase 3 + head, in two 128-col halves of W2.
    float s[2][4] = {};
#pragma unroll
    for (int h = 0; h < 2; ++h) {
        __syncthreads();   // previous wbuf readers done (and h1 writes done)
        for (int idx = t; idx < 128 * 32; idx += THREADS) {
            int row = idx >> 5, kc = (idx & 31) * 8;
            bf16x8 v = *reinterpret_cast<const bf16x8*>(
                W2b + (size_t)(h * 128 + row) * 256 + kc);
            *reinterpret_cast<bf16x8*>(&ovl.wbuf[row * 264 + kc]) = v;
        }
        __syncthreads();
        f32x4 acc[2][2] = {};
#pragma unroll
        for (int k0 = 0; k0 < 256; k0 += 32) {
            bf16x8 af[2];
#pragma unroll
            for (int i = 0; i < 2; ++i)
                af[i] = *reinterpret_cast<const bf16x8*>(
                    &bufA[(wm * 32 + i * 16 + l16) * 264 + k0 + q * 8]);
#pragma unroll
            for (int jj = 0; jj < 2; ++jj) {
                int lcol = wn * 32 + jj * 16 + l16;
                bf16x8 bv = *reinterpret_cast<const bf16x8*>(
                    &ovl.wbuf[lcol * 264 + k0 + q * 8]);
                acc[0][jj] = __builtin_amdgcn_mfma_f32_16x16x32_bf16(af[0], bv, acc[0][jj], 0, 0, 0);
                acc[1][jj] = __builtin_amdgcn_mfma_f32_16x16x32_bf16(af[1], bv, acc[1][jj], 0, 0, 0);
            }
        }
#pragma unroll
        for (int jj = 0; jj < 2; ++jj) {
            int col = h * 128 + wn * 32 + jj * 16 + l16;
            float bb = b2[col], ww = W3[col];
#pragma unroll
            for (int i = 0; i < 2; ++i)
#pragma unroll
                for (int r = 0; r < 4; ++r)
                    s[i][r] = fmaf(fmaxf(acc[i][jj][r] + bb, 0.f), ww, s[i][r]);
        }
    }
#pragma unroll
    for (int off = 1; off < 16; off <<= 1)
#pragma unroll
        for (int i = 0; i < 2; ++i)
#pragma unroll
            for (int r = 0; r < 4; ++r)
                s[i][r] += __shfl_xor(s[i][r], off);
    if (l16 == 0)
#pragma unroll
        for (int i = 0; i < 2; ++i)
#pragma unroll
            for (int r = 0; r < 4; ++r)
                part[wm * 32 + i * 16 + q * 4 + r][wn] = s[i][r];
    __syncthreads();
    if (t < 64) {
        int node = r0 + t;
        if (node < M) {
            float v = part[t][0] + part[t][1] + part[t][2] + part[t][3] + b3[0];
            out[node] = 1.0f / (1.0f + expf(-v));
        }
    }
}

// ===========================================================================
// Legacy 4-kernel path (verbatim, harness-verified @126.5us) — used only if
// the cooperative launch is rejected.
// ===========================================================================
constexpr int PREP_XB = 1250, PREP_WB = 128;
__global__ __launch_bounds__(256)
void prep_kernel(const float* __restrict__ x,
                 const float* __restrict__ W_rel, const float* __restrict__ W_root,
                 const float* __restrict__ W1, const float* __restrict__ W2,
                 u16* __restrict__ x_bf,
                 u16* __restrict__ Wcat, u16* __restrict__ W1b, u16* __restrict__ W2b,
                 int* __restrict__ gcnt) {
    const int bid = blockIdx.x, t = threadIdx.x;
    if (bid < PREP_XB) {
        int idx = bid * 256 + t;
        if (idx >= N_NODES * 32) return;
        int row = idx >> 5, c = (idx & 31) * 4;
        float4 v = *reinterpret_cast<const float4*>(x + (size_t)row * D_IN + c);
        ushort4 o;
        o.x = f2bf(v.x); o.y = f2bf(v.y); o.z = f2bf(v.z); o.w = f2bf(v.w);
        *reinterpret_cast<ushort4*>(x_bf + (size_t)row * D_IN + c) = o;
    } else if (bid < PREP_XB + PREP_WB) {
        int idx4 = ((bid - PREP_XB) * 256 + t) * 4;
        const float* src;
        u16* dst;
        if (idx4 < 32768) {
            int n = idx4 >> 8, k = idx4 & 255;
            src = (k < 128) ? W_rel + n * 128 + k : W_root + n * 128 + (k - 128);
            dst = Wcat + idx4;
        } else if (idx4 < 65536) {
            src = W1 + (idx4 - 32768);
            dst = W1b + (idx4 - 32768);
        } else {
            src = W2 + (idx4 - 65536);
            dst = W2b + (idx4 - 65536);
        }
        float4 v = *reinterpret_cast<const float4*>(src);
        ushort4 o;
        o.x = f2bf(v.x); o.y = f2bf(v.y); o.z = f2bf(v.z); o.w = f2bf(v.w);
        *reinterpret_cast<ushort4*>(dst) = o;
    } else {
        for (int i = t; i < NB; i += 256) gcnt[i] = 0;
    }
}

__global__ __launch_bounds__(256)
void binsort_a(const int* __restrict__ ei, int* __restrict__ gcnt,
               int* __restrict__ buckets, int E) {
    __shared__ int lcnt[NB], gbase[NB];
    const int t = threadIdx.x;
    for (int i = t; i < NB; i += 256) lcnt[i] = 0;
    __syncthreads();
    const int e0 = blockIdx.x * EPB_A + t;
    int packed[8], lpos[8], bb[8];
#pragma unroll
    for (int j = 0; j < 8; ++j) {
        int e = e0 + j * 256;
        if (e < E) {
            int s = ei[e], d = ei[E + e];
            int b = d >> 5;
            bb[j] = b;
            packed[j] = ((d & 31) << 16) | s;
            lpos[j] = atomicAdd(&lcnt[b], 1);
        } else bb[j] = -1;
    }
    __syncthreads();
    for (int i = t; i < NB; i += 256)
        gbase[i] = atomicAdd(&gcnt[i], lcnt[i]);
    __syncthreads();
#pragma unroll
    for (int j = 0; j < 8; ++j)
        if (bb[j] >= 0)
            buckets[bb[j] * BCAP + gbase[bb[j]] + lpos[j]] = packed[j];
}

__global__ __launch_bounds__(512)
void sortgather(const int* __restrict__ gcnt, const int* __restrict__ buckets,
                const u16* __restrict__ x_bf, u16* __restrict__ agg_bf, int M) {
    __shared__ int edges[BCAP];
    __shared__ u16 ssrc[BCAP];
    __shared__ int deg[32], cur[32], sbeg[32];
    const int b = blockIdx.x, t = threadIdx.x;
    const int w = t >> 6, lane = t & 63;
    if (t < 32) deg[t] = 0;
    __syncthreads();
    int cnt = gcnt[b]; if (cnt > BCAP) cnt = BCAP;
    for (int i = t; i < cnt; i += 512) {
        int p = buckets[b * BCAP + i];
        edges[i] = p;
        atomicAdd(&deg[p >> 16], 1);
    }
    __syncthreads();
    if (t < 32) {
        int d = deg[t];
        int incl = d;
#pragma unroll
        for (int off = 1; off < 32; off <<= 1) {
            int o = __shfl_up(incl, off);
            if (t >= off) incl += o;
        }
        int excl = incl - d;
        cur[t] = excl;
        sbeg[t] = excl;
    }
    __syncthreads();
    for (int i = t; i < cnt; i += 512) {
        int p = edges[i];
        int pos = atomicAdd(&cur[p >> 16], 1);
        ssrc[pos] = (u16)(p & 0xffff);
    }
    __syncthreads();
    const int c = (lane & 31) * 4;
    const int r = lane >> 5;
#pragma unroll
    for (int j = 0; j < 4; ++j) {
        int ln = w * 4 + j;
        int beg = sbeg[ln], dg = deg[ln];
        int half = (dg + 1) >> 1;
        int i = beg + (r ? half : 0);
        const int i1 = r ? beg + dg : beg + half;
        float4 a0 = {0, 0, 0, 0}, a1 = {0, 0, 0, 0};
        float4 a2 = {0, 0, 0, 0}, a3 = {0, 0, 0, 0};
        for (; i + 4 <= i1; i += 4) {
            int s0 = ssrc[i + 0], s1 = ssrc[i + 1];
            int s2 = ssrc[i + 2], s3 = ssrc[i + 3];
            ushort4 v0 = *reinterpret_cast<const ushort4*>(x_bf + (size_t)s0 * D_IN + c);
            ushort4 v1 = *reinterpret_cast<const ushort4*>(x_bf + (size_t)s1 * D_IN + c);
            ushort4 v2 = *reinterpret_cast<const ushort4*>(x_bf + (size_t)s2 * D_IN + c);
            ushort4 v3 = *reinterpret_cast<const ushort4*>(x_bf + (size_t)s3 * D_IN + c);
            a0.x += bf2f(v0.x); a0.y += bf2f(v0.y); a0.z += bf2f(v0.z); a0.w += bf2f(v0.w);
            a1.x += bf2f(v1.x); a1.y += bf2f(v1.y); a1.z += bf2f(v1.z); a1.w += bf2f(v1.w);
            a2.x += bf2f(v2.x); a2.y += bf2f(v2.y); a2.z += bf2f(v2.z); a2.w += bf2f(v2.w);
            a3.x += bf2f(v3.x); a3.y += bf2f(v3.y); a3.z += bf2f(v3.z); a3.w += bf2f(v3.w);
        }
        for (; i < i1; ++i) {
            int s = ssrc[i];
            ushort4 v = *reinterpret_cast<const ushort4*>(x_bf + (size_t)s * D_IN + c);
            a0.x += bf2f(v.x); a0.y += bf2f(v.y); a0.z += bf2f(v.z); a0.w += bf2f(v.w);
        }
        a0.x += a1.x + a2.x + a3.x;
        a0.y += a1.y + a2.y + a3.y;
        a0.z += a1.z + a2.z + a3.z;
        a0.w += a1.w + a2.w + a3.w;
        a0.x += __shfl_xor(a0.x, 32);
        a0.y += __shfl_xor(a0.y, 32);
        a0.z += __shfl_xor(a0.z, 32);
        a0.w += __shfl_xor(a0.w, 32);
        int node = b * 32 + ln;
        if (r == 0 && node < M) {
            ushort4 o;
            o.x = f2bf(a0.x); o.y = f2bf(a0.y); o.z = f2bf(a0.z); o.w = f2bf(a0.w);
            *reinterpret_cast<ushort4*>(agg_bf + (size_t)node * D_IN + c) = o;
        }
    }
}

__global__ __launch_bounds__(512)
void fused_mlp(const u16* __restrict__ agg_bf, const u16* __restrict__ x_bf,
               const u16* __restrict__ Wcat, const u16* __restrict__ W1b,
               const u16* __restrict__ W2b,
               const float* __restrict__ b_rel, const float* __restrict__ b1,
               const float* __restrict__ b2, const float* __restrict__ W3,
               const float* __restrict__ b3, float* __restrict__ out, int M) {
    __shared__ u16 bufA[64 * 264];
    __shared__ u16 bufH0[64 * 136];
    __shared__ u16 wbuf[34816];
    __shared__ float part[64][4];
    const int t = threadIdx.x, b = blockIdx.x;
    const int w = t >> 6, lane = t & 63;
    const int wm = w >> 2, wn = w & 3;
    const int l16 = lane & 15, q = lane >> 4;
    const int r0 = b * 64;
    for (int idx = t; idx < 64 * 16; idx += 512) {
        int row = idx >> 4, kc = (idx & 15) * 8;
        int gr = r0 + row; if (gr >= M) gr = M - 1;
        bf16x8 v = *reinterpret_cast<const bf16x8*>(agg_bf + (size_t)gr * D_IN + kc);
        *reinterpret_cast<bf16x8*>(&bufA[row * 264 + kc]) = v;
        bf16x8 vx = *reinterpret_cast<const bf16x8*>(x_bf + (size_t)gr * D_IN + kc);
        *reinterpret_cast<bf16x8*>(&bufA[row * 264 + 128 + kc]) = vx;
    }
    for (int idx = t; idx < 128 * 32; idx += 512) {
        int row = idx >> 5, kc = (idx & 31) * 8;
        bf16x8 v = *reinterpret_cast<const bf16x8*>(Wcat + (size_t)row * 256 + kc);
        *reinterpret_cast<bf16x8*>(&wbuf[row * 264 + kc]) = v;
    }
    __syncthreads();
    {
        f32x4 acc[2][2] = {};
#pragma unroll
        for (int k0 = 0; k0 < 256; k0 += 32) {
            bf16x8 af[2];
#pragma unroll
            for (int i = 0; i < 2; ++i)
                af[i] = *reinterpret_cast<const bf16x8*>(
                    &bufA[(wm * 32 + i * 16 + l16) * 264 + k0 + q * 8]);
#pragma unroll
            for (int jj = 0; jj < 2; ++jj) {
                int col = wn * 32 + jj * 16 + l16;
                bf16x8 bv = *reinterpret_cast<const bf16x8*>(
                    &wbuf[col * 264 + k0 + q * 8]);
                acc[0][jj] = __builtin_amdgcn_mfma_f32_16x16x32_bf16(af[0], bv, acc[0][jj], 0, 0, 0);
                acc[1][jj] = __builtin_amdgcn_mfma_f32_16x16x32_bf16(af[1], bv, acc[1][jj], 0, 0, 0);
            }
        }
#pragma unroll
        for (int i = 0; i < 2; ++i)
#pragma unroll
            for (int jj = 0; jj < 2; ++jj) {
                int col = wn * 32 + jj * 16 + l16;
                float bb = b_rel[col];
#pragma unroll
                for (int r = 0; r < 4; ++r) {
                    int row = wm * 32 + i * 16 + q * 4 + r;
                    bufH0[row * 136 + col] = f2bf(acc[i][jj][r] + bb);
                }
            }
    }
    __syncthreads();
    for (int idx = t; idx < 256 * 16; idx += 512) {
        int row = idx >> 4, kc = (idx & 15) * 8;
        bf16x8 v = *reinterpret_cast<const bf16x8*>(W1b + (size_t)row * 128 + kc);
        *reinterpret_cast<bf16x8*>(&wbuf[row * 136 + kc]) = v;
    }
    __syncthreads();
    {
        f32x4 acc[2][4] = {};
#pragma unroll
        for (int k0 = 0; k0 < 128; k0 += 32) {
            bf16x8 af[2];
#pragma unroll
            for (int i = 0; i < 2; ++i)
                af[i] = *reinterpret_cast<const bf16x8*>(
                    &bufH0[(wm * 32 + i * 16 + l16) * 136 + k0 + q * 8]);
#pragma unroll
            for (int jj = 0; jj < 4; ++jj) {
                int col = wn * 64 + jj * 16 + l16;
                bf16x8 bv = *reinterpret_cast<const bf16x8*>(
                    &wbuf[col * 136 + k0 + q * 8]);
                acc[0][jj] = __builtin_amdgcn_mfma_f32_16x16x32_bf16(af[0], bv, acc[0][jj], 0, 0, 0);
                acc[1][jj] = __builtin_amdgcn_mfma_f32_16x16x32_bf16(af[1], bv, acc[1][jj], 0, 0, 0);
            }
        }
#pragma unroll
        for (int i = 0; i < 2; ++i)
#pragma unroll
            for (int jj = 0; jj < 4; ++jj) {
                int col = wn * 64 + jj * 16 + l16;
                float bb = b1[col];
#pragma unroll
                for (int r = 0; r < 4; ++r) {
                    int row = wm * 32 + i * 16 + q * 4 + r;
                    bufA[row * 264 + col] = f2bf(fmaxf(acc[i][jj][r] + bb, 0.f));
                }
            }
    }
    float s[2][4] = {};
#pragma unroll
    for (int h = 0; h < 2; ++h) {
        __syncthreads();
        for (int idx = t; idx < 128 * 32; idx += 512) {
            int row = idx >> 5, kc = (idx & 31) * 8;
            bf16x8 v = *reinterpret_cast<const bf16x8*>(
                W2b + (size_t)(h * 128 + row) * 256 + kc);
            *reinterpret_cast<bf16x8*>(&wbuf[row * 264 + kc]) = v;
        }
        __syncthreads();
        f32x4 acc[2][2] = {};
#pragma unroll
        for (int k0 = 0; k0 < 256; k0 += 32) {
            bf16x8 af[2];
#pragma unroll
            for (int i = 0; i < 2; ++i)
                af[i] = *reinterpret_cast<const bf16x8*>(
                    &bufA[(wm * 32 + i * 16 + l16) * 264 + k0 + q * 8]);
#pragma unroll
            for (int jj = 0; jj < 2; ++jj) {
                int lcol = wn * 32 + jj * 16 + l16;
                bf16x8 bv = *reinterpret_cast<const bf16x8*>(
                    &wbuf[lcol * 264 + k0 + q * 8]);
                acc[0][jj] = __builtin_amdgcn_mfma_f32_16x16x32_bf16(af[0], bv, acc[0][jj], 0, 0, 0);
                acc[1][jj] = __builtin_amdgcn_mfma_f32_16x16x32_bf16(af[1], bv, acc[1][jj], 0, 0, 0);
            }
        }
#pragma unroll
        for (int jj = 0; jj < 2; ++jj) {
            int col = h * 128 + wn * 32 + jj * 16 + l16;
            float bb = b2[col], ww = W3[col];
#pragma unroll
            for (int i = 0; i < 2; ++i)
#pragma unroll
                for (int r = 0; r < 4; ++r)
                    s[i][r] = fmaf(fmaxf(acc[i][jj][r] + bb, 0.f), ww, s[i][r]);
        }
    }
#pragma unroll
    for (int off = 1; off < 16; off <<= 1)
#pragma unroll
        for (int i = 0; i < 2; ++i)
#pragma unroll
            for (int r = 0; r < 4; ++r)
                s[i][r] += __shfl_xor(s[i][r], off);
    if (l16 == 0)
#pragma unroll
        for (int i = 0; i < 2; ++i)
#pragma unroll
            for (int r = 0; r < 4; ++r)
                part[wm * 32 + i * 16 + q * 4 + r][wn] = s[i][r];
    __syncthreads();
    if (t < 64) {
        int node = r0 + t;
        if (node < M) {
            float v = part[t][0] + part[t][1] + part[t][2] + part[t][3] + b3[0];
            out[node] = 1.0f / (1.0f + expf(-v));
        }
    }
}

extern "C" void kernel_launch(void* const* d_in, const int* in_sizes, int n_in,
                              void* d_out, int out_size, void* d_ws, size_t ws_size,
                              hipStream_t stream) {
    const float* x      = (const float*)d_in[0];
    const int*   ei     = (const int*)d_in[1];   // [2, E]: src row then dst row
    const float* W_rel  = (const float*)d_in[2];
    const float* b_rel  = (const float*)d_in[3];
    const float* W_root = (const float*)d_in[4];
    const float* W1     = (const float*)d_in[5];
    const float* b1     = (const float*)d_in[6];
    const float* W2     = (const float*)d_in[7];
    const float* b2     = (const float*)d_in[8];
    const float* W3     = (const float*)d_in[9];
    const float* b3     = (const float*)d_in[10];
    float* out = (float*)d_out;
    int E = in_sizes[1] / 2;
    int M = N_NODES;

    char* p = (char*)d_ws;
    auto carve = [&](size_t bytes) { char* r = p; p += (bytes + 63) & ~size_t(63); return r; };
    u16* x_bf   = (u16*)carve((size_t)N_NODES * D_IN * 2);   // dense bf16 x
    u16* agg_bf = (u16*)carve((size_t)N_NODES * D_IN * 2);   // legacy path only
    u16* Wcat   = (u16*)carve(128 * 256 * 2);
    u16* W1b    = (u16*)carve(256 * 128 * 2);
    u16* W2b    = (u16*)carve(256 * 256 * 2);
    int* gcnt    = (int*)carve(NB * 4);
    int* buckets = (int*)carve((size_t)NB * BCAP * 4);       // 3.85 MB

    hipMemsetAsync(gcnt, 0, NB * sizeof(int), stream);

    void* args[] = { &x, &ei, &W_rel, &W_root, &W1, &W2, &b_rel, &b1, &b2, &W3, &b3,
                     &x_bf, &Wcat, &W1b, &W2b, &gcnt, &buckets, &out, &E, &M };
    hipError_t err = hipLaunchCooperativeKernel(
        reinterpret_cast<const void*>(&mega), dim3(GRID), dim3(THREADS),
        args, 0u, stream);
    if (err != hipSuccess) {
        // Fallback: verified 4-kernel path (prep re-zeroes gcnt itself).
        prep_kernel<<<PREP_XB + PREP_WB + 1, 256, 0, stream>>>(
            x, W_rel, W_root, W1, W2, x_bf, Wcat, W1b, W2b, gcnt);
        binsort_a<<<(E + EPB_A - 1) / EPB_A, 256, 0, stream>>>(ei, gcnt, buckets, E);
        sortgather<<<NB, 512, 0, stream>>>(gcnt, buckets, x_bf, agg_bf, N_NODES);
        fused_mlp<<<(N_NODES + 63) / 64, 512, 0, stream>>>(
            agg_bf, x_bf, Wcat, W1b, W2b, b_rel, b1, b2, W3, b3, out, N_NODES);
    }
}

// Round 3
// 125.641 us; speedup vs baseline: 1.9138x; 1.9138x over previous
//
#include <hip/hip_runtime.h>
#include <hip/hip_bf16.h>
#include <cmath>

constexpr int N_NODES = 10000;
constexpr int D_IN = 128;   // GraphConv dim
constexpr int H_DIM = 256;  // MLP hidden

// Bucket geometry: bucket = dst>>5 (32 nodes/bucket), 313 buckets.
constexpr int NB = 313;
constexpr int BCAP = 3072;      // avg 2045 edges/bucket, sigma ~45 -> 22-sigma margin
constexpr int EPB_A = 2048;     // edges per K1 block (256 thr x 8)
constexpr int K1_GRID = 313;    // 313*2048 = 640k >= E
constexpr int K2_GRID = 157;    // (N_NODES+63)/64, 64 nodes (2 buckets) per block
constexpr int K2_THREADS = 1024;

typedef unsigned short u16;
typedef short bf16x8 __attribute__((ext_vector_type(8)));  // 8 bf16 = 4 VGPRs
typedef float f32x4 __attribute__((ext_vector_type(4)));

__device__ inline u16 f2bf(float f) {
    return __builtin_bit_cast(u16, __float2bfloat16(f));  // RNE hw cvt
}
__device__ inline float bf2f(u16 u) {
    unsigned int v = (unsigned int)u << 16;
    return __builtin_bit_cast(float, v);
}

// ===========================================================================
// K1: prep + binsort fused. 313 blocks x 256 thr.
//  - grid-strided x fp32->bf16 cast (320000 float4 chunks / 80128 threads)
//  - weight casts: Wcat=[W_rel|W_root] 128x256, W1b 256x128, W2b 256x256
//  - binsort slice: 2048 edges/block, LDS hist + one global cursor
//    reservation per (block,bucket) -> contiguous write runs.
// packed = (dst & 31) << 16 | src  (src < 65536). gcnt pre-zeroed by memset.
// ===========================================================================
__global__ __launch_bounds__(256)
void prep_binsort(const float* __restrict__ x, const int* __restrict__ ei,
                  const float* __restrict__ W_rel, const float* __restrict__ W_root,
                  const float* __restrict__ W1, const float* __restrict__ W2,
                  u16* __restrict__ x_bf, u16* __restrict__ Wcat,
                  u16* __restrict__ W1b, u16* __restrict__ W2b,
                  int* __restrict__ gcnt, int* __restrict__ buckets, int E)
{
    __shared__ int lcnt[NB], gbase[NB];
    const int t = threadIdx.x, blk = blockIdx.x;
    const int tid = blk * 256 + t;

    for (int i = t; i < NB; i += 256) lcnt[i] = 0;

    // x cast (streaming, overlaps with binsort's LDS work below)
    for (int idx = tid; idx < N_NODES * 32; idx += K1_GRID * 256) {
        int row = idx >> 5, c = (idx & 31) * 4;
        float4 v = *reinterpret_cast<const float4*>(x + (size_t)row * D_IN + c);
        ushort4 o;
        o.x = f2bf(v.x); o.y = f2bf(v.y); o.z = f2bf(v.z); o.w = f2bf(v.w);
        *reinterpret_cast<ushort4*>(x_bf + (size_t)row * D_IN + c) = o;
    }
    // weight casts (32768 float4 chunks; threads 0..32767)
    if (tid < 32768) {
        int idx4 = tid * 4;
        const float* src;
        u16* dst;
        if (idx4 < 32768) {            // Wcat = [W_rel|W_root]
            int n = idx4 >> 8, k = idx4 & 255;
            src = (k < 128) ? W_rel + n * 128 + k : W_root + n * 128 + (k - 128);
            dst = Wcat + idx4;
        } else if (idx4 < 65536) {     // W1
            src = W1 + (idx4 - 32768);
            dst = W1b + (idx4 - 32768);
        } else {                       // W2
            src = W2 + (idx4 - 65536);
            dst = W2b + (idx4 - 65536);
        }
        float4 v = *reinterpret_cast<const float4*>(src);
        ushort4 o;
        o.x = f2bf(v.x); o.y = f2bf(v.y); o.z = f2bf(v.z); o.w = f2bf(v.w);
        *reinterpret_cast<ushort4*>(dst) = o;
    }
    __syncthreads();

    // binsort slice (verbatim binsort_a body)
    const int e0 = blk * EPB_A + t;
    int packed[8], lpos[8], bb[8];
#pragma unroll
    for (int j = 0; j < 8; ++j) {
        int e = e0 + j * 256;
        if (e < E) {
            int s = ei[e], d = ei[E + e];
            int b = d >> 5;
            bb[j] = b;
            packed[j] = ((d & 31) << 16) | s;
            lpos[j] = atomicAdd(&lcnt[b], 1);
        } else bb[j] = -1;
    }
    __syncthreads();
    for (int i = t; i < NB; i += 256)
        gbase[i] = atomicAdd(&gcnt[i], lcnt[i]);
    __syncthreads();
#pragma unroll
    for (int j = 0; j < 8; ++j)
        if (bb[j] >= 0)
            buckets[bb[j] * BCAP + gbase[bb[j]] + lpos[j]] = packed[j];
}

// ===========================================================================
// K2: sort + gather + fused MLP. 157 blocks x 1024 thr (16 waves/CU, 2x the
// mega experiment's occupancy for the latency-bound gather). Block b owns
// buckets 2b,2b+1 = nodes 64b..64b+63.
//  - LDS counting-sort of both buckets (hist -> scan -> scatter)
//  - gather straight into the MFMA A-tile (bufA cols 0..127); x rows into
//    cols 128..255 (no agg_bf global round-trip)
//  - validated 3-phase MFMA MLP + head on waves 0..7 (tiling unchanged)
// LDS 122.6 KB -> 1 block/CU; 16 waves = 4/SIMD during gather.
// ===========================================================================
__global__ __launch_bounds__(K2_THREADS)
void sortgather_mlp(const int* __restrict__ gcnt, const int* __restrict__ buckets,
                    const u16* __restrict__ x_bf,
                    const u16* __restrict__ Wcat, const u16* __restrict__ W1b,
                    const u16* __restrict__ W2b,
                    const float* __restrict__ b_rel, const float* __restrict__ b1,
                    const float* __restrict__ b2, const float* __restrict__ W3,
                    const float* __restrict__ b3, float* __restrict__ out, int M)
{
    __shared__ alignas(16) u16 bufA[64 * 264];   // 33.8 KB: [agg|x], later h1
    __shared__ alignas(16) u16 bufH0[64 * 136];  // 17.4 KB
    union alignas(16) Ovl {
        struct { int edges[2][BCAP]; u16 ssrc[2][BCAP]; } s;  // sort scratch 36.9 KB
        u16 wbuf[34816];                                      // weight tiles 69.6 KB
    };
    __shared__ Ovl ovl;
    __shared__ int deg[2][32], cur[2][32], sbeg[2][32];
    __shared__ float part[64][4];

    const int t = threadIdx.x, blk = blockIdx.x;
    const int w = t >> 6, lane = t & 63;          // w in 0..15
    const int wm = (w >> 2) & 1, wn = w & 3;      // MFMA tiling (waves 0..7)
    const int l16 = lane & 15, q = lane >> 4;
    const int r0 = blk * 64;

    int cnt[2];
#pragma unroll
    for (int k = 0; k < 2; ++k) {
        int bk = blk * 2 + k;
        int c = (bk < NB) ? gcnt[bk] : 0;   // block 156's 2nd bucket: none
        cnt[k] = c > BCAP ? BCAP : c;
    }
    if (t < 64) deg[t >> 5][t & 31] = 0;
    __syncthreads();

    // stage self x rows -> bufA cols 128..255 (1024 chunks / 1024 thr)
    for (int idx = t; idx < 64 * 16; idx += K2_THREADS) {
        int row = idx >> 4, kc = (idx & 15) * 8;
        int gr = r0 + row; if (gr >= M) gr = M - 1;
        bf16x8 vx = *reinterpret_cast<const bf16x8*>(x_bf + (size_t)gr * D_IN + kc);
        *reinterpret_cast<bf16x8*>(&bufA[row * 264 + 128 + kc]) = vx;
    }
    // load bucket edges + per-node hist
#pragma unroll
    for (int k = 0; k < 2; ++k) {
        int bk = blk * 2 + k;
        for (int i = t; i < cnt[k]; i += K2_THREADS) {
            int p = buckets[bk * BCAP + i];
            ovl.s.edges[k][i] = p;
            atomicAdd(&deg[k][p >> 16], 1);
        }
    }
    __syncthreads();
    if (t < 64) {   // two 32-wide exclusive scans (width-32 shfl segments)
        int k = t >> 5, tl = t & 31;
        int d = deg[k][tl], incl = d;
#pragma unroll
        for (int off = 1; off < 32; off <<= 1) {
            int o = __shfl_up(incl, off, 32);
            if (tl >= off) incl += o;
        }
        cur[k][tl] = incl - d;
        sbeg[k][tl] = incl - d;
    }
    __syncthreads();
#pragma unroll
    for (int k = 0; k < 2; ++k)
        for (int i = t; i < cnt[k]; i += K2_THREADS) {
            int p = ovl.s.edges[k][i];
            int pos = atomicAdd(&cur[k][p >> 16], 1);
            ovl.s.ssrc[k][pos] = (u16)(p & 0xffff);
        }
    __syncthreads();

    // gather: wave w (of 16) -> nodes w*4..w*4+3 of the 64; half-wave per
    // node-half, ILP x4; agg -> bufA cols 0..127
    {
        const int c4 = (lane & 31) * 4;
        const int rh = lane >> 5;
#pragma unroll
        for (int j = 0; j < 4; ++j) {
            int ln = w * 4 + j;                 // 0..63
            int k = ln >> 5, lnn = ln & 31;
            const u16* sp = ovl.s.ssrc[k];
            int beg = sbeg[k][lnn], dg = deg[k][lnn];
            int half = (dg + 1) >> 1;
            int i = beg + (rh ? half : 0);
            const int i1 = rh ? beg + dg : beg + half;
            float4 a0 = {0, 0, 0, 0}, a1 = {0, 0, 0, 0};
            float4 a2 = {0, 0, 0, 0}, a3 = {0, 0, 0, 0};
            for (; i + 4 <= i1; i += 4) {
                int s0 = sp[i + 0], s1 = sp[i + 1];
                int s2 = sp[i + 2], s3 = sp[i + 3];
                ushort4 v0 = *reinterpret_cast<const ushort4*>(x_bf + (size_t)s0 * D_IN + c4);
                ushort4 v1 = *reinterpret_cast<const ushort4*>(x_bf + (size_t)s1 * D_IN + c4);
                ushort4 v2 = *reinterpret_cast<const ushort4*>(x_bf + (size_t)s2 * D_IN + c4);
                ushort4 v3 = *reinterpret_cast<const ushort4*>(x_bf + (size_t)s3 * D_IN + c4);
                a0.x += bf2f(v0.x); a0.y += bf2f(v0.y); a0.z += bf2f(v0.z); a0.w += bf2f(v0.w);
                a1.x += bf2f(v1.x); a1.y += bf2f(v1.y); a1.z += bf2f(v1.z); a1.w += bf2f(v1.w);
                a2.x += bf2f(v2.x); a2.y += bf2f(v2.y); a2.z += bf2f(v2.z); a2.w += bf2f(v2.w);
                a3.x += bf2f(v3.x); a3.y += bf2f(v3.y); a3.z += bf2f(v3.z); a3.w += bf2f(v3.w);
            }
            for (; i < i1; ++i) {
                int s = sp[i];
                ushort4 v = *reinterpret_cast<const ushort4*>(x_bf + (size_t)s * D_IN + c4);
                a0.x += bf2f(v.x); a0.y += bf2f(v.y); a0.z += bf2f(v.z); a0.w += bf2f(v.w);
            }
            a0.x += a1.x + a2.x + a3.x;
            a0.y += a1.y + a2.y + a3.y;
            a0.z += a1.z + a2.z + a3.z;
            a0.w += a1.w + a2.w + a3.w;
            a0.x += __shfl_xor(a0.x, 32);
            a0.y += __shfl_xor(a0.y, 32);
            a0.z += __shfl_xor(a0.z, 32);
            a0.w += __shfl_xor(a0.w, 32);
            if (rh == 0) {
                ushort4 o;
                o.x = f2bf(a0.x); o.y = f2bf(a0.y); o.z = f2bf(a0.z); o.w = f2bf(a0.w);
                *reinterpret_cast<ushort4*>(&bufA[ln * 264 + c4]) = o;
            }
        }
    }
    __syncthreads();   // sort scratch dead; bufA agg half complete

    // stage Wcat -> wbuf (overlays sort scratch)
    for (int idx = t; idx < 128 * 32; idx += K2_THREADS) {
        int row = idx >> 5, kc = (idx & 31) * 8;
        bf16x8 v = *reinterpret_cast<const bf16x8*>(Wcat + (size_t)row * 256 + kc);
        *reinterpret_cast<bf16x8*>(&ovl.wbuf[row * 264 + kc]) = v;
    }
    __syncthreads();

    // Phase 1: h0[64][128] = A @ Wcat^T + b_rel   (waves 0..7)
    if (w < 8) {
        f32x4 acc[2][2] = {};
#pragma unroll
        for (int k0 = 0; k0 < 256; k0 += 32) {
            bf16x8 af[2];
#pragma unroll
            for (int i = 0; i < 2; ++i)
                af[i] = *reinterpret_cast<const bf16x8*>(
                    &bufA[(wm * 32 + i * 16 + l16) * 264 + k0 + q * 8]);
#pragma unroll
            for (int jj = 0; jj < 2; ++jj) {
                int col = wn * 32 + jj * 16 + l16;
                bf16x8 bv = *reinterpret_cast<const bf16x8*>(
                    &ovl.wbuf[col * 264 + k0 + q * 8]);
                acc[0][jj] = __builtin_amdgcn_mfma_f32_16x16x32_bf16(af[0], bv, acc[0][jj], 0, 0, 0);
                acc[1][jj] = __builtin_amdgcn_mfma_f32_16x16x32_bf16(af[1], bv, acc[1][jj], 0, 0, 0);
            }
        }
#pragma unroll
        for (int i = 0; i < 2; ++i)
#pragma unroll
            for (int jj = 0; jj < 2; ++jj) {
                int col = wn * 32 + jj * 16 + l16;
                float bb = b_rel[col];
#pragma unroll
                for (int r = 0; r < 4; ++r) {
                    int row = wm * 32 + i * 16 + q * 4 + r;
                    bufH0[row * 136 + col] = f2bf(acc[i][jj][r] + bb);
                }
            }
    }
    __syncthreads();   // wbuf reads + bufH0 writes complete

    // Stage W1b [256][128] (stride 136).
    for (int idx = t; idx < 256 * 16; idx += K2_THREADS) {
        int row = idx >> 4, kc = (idx & 15) * 8;
        bf16x8 v = *reinterpret_cast<const bf16x8*>(W1b + (size_t)row * 128 + kc);
        *reinterpret_cast<bf16x8*>(&ovl.wbuf[row * 136 + kc]) = v;
    }
    __syncthreads();

    // Phase 2: h1[64][256] = relu(h0 @ W1^T + b1); h1 overlays bufA
    if (w < 8) {
        f32x4 acc[2][4] = {};
#pragma unroll
        for (int k0 = 0; k0 < 128; k0 += 32) {
            bf16x8 af[2];
#pragma unroll
            for (int i = 0; i < 2; ++i)
                af[i] = *reinterpret_cast<const bf16x8*>(
                    &bufH0[(wm * 32 + i * 16 + l16) * 136 + k0 + q * 8]);
#pragma unroll
            for (int jj = 0; jj < 4; ++jj) {
                int col = wn * 64 + jj * 16 + l16;
                bf16x8 bv = *reinterpret_cast<const bf16x8*>(
                    &ovl.wbuf[col * 136 + k0 + q * 8]);
                acc[0][jj] = __builtin_amdgcn_mfma_f32_16x16x32_bf16(af[0], bv, acc[0][jj], 0, 0, 0);
                acc[1][jj] = __builtin_amdgcn_mfma_f32_16x16x32_bf16(af[1], bv, acc[1][jj], 0, 0, 0);
            }
        }
#pragma unroll
        for (int i = 0; i < 2; ++i)
#pragma unroll
            for (int jj = 0; jj < 4; ++jj) {
                int col = wn * 64 + jj * 16 + l16;
                float bb = b1[col];
#pragma unroll
                for (int r = 0; r < 4; ++r) {
                    int row = wm * 32 + i * 16 + q * 4 + r;
                    bufA[row * 264 + col] = f2bf(fmaxf(acc[i][jj][r] + bb, 0.f));
                }
            }
    }

    // Phase 3 + head, in two 128-col halves of W2.
    float s[2][4] = {};
#pragma unroll
    for (int h = 0; h < 2; ++h) {
        __syncthreads();   // previous wbuf readers done (and h1 writes done)
        for (int idx = t; idx < 128 * 32; idx += K2_THREADS) {
            int row = idx >> 5, kc = (idx & 31) * 8;
            bf16x8 v = *reinterpret_cast<const bf16x8*>(
                W2b + (size_t)(h * 128 + row) * 256 + kc);
            *reinterpret_cast<bf16x8*>(&ovl.wbuf[row * 264 + kc]) = v;
        }
        __syncthreads();
        if (w < 8) {
            f32x4 acc[2][2] = {};
#pragma unroll
            for (int k0 = 0; k0 < 256; k0 += 32) {
                bf16x8 af[2];
#pragma unroll
                for (int i = 0; i < 2; ++i)
                    af[i] = *reinterpret_cast<const bf16x8*>(
                        &bufA[(wm * 32 + i * 16 + l16) * 264 + k0 + q * 8]);
#pragma unroll
                for (int jj = 0; jj < 2; ++jj) {
                    int lcol = wn * 32 + jj * 16 + l16;
                    bf16x8 bv = *reinterpret_cast<const bf16x8*>(
                        &ovl.wbuf[lcol * 264 + k0 + q * 8]);
                    acc[0][jj] = __builtin_amdgcn_mfma_f32_16x16x32_bf16(af[0], bv, acc[0][jj], 0, 0, 0);
                    acc[1][jj] = __builtin_amdgcn_mfma_f32_16x16x32_bf16(af[1], bv, acc[1][jj], 0, 0, 0);
                }
            }
#pragma unroll
            for (int jj = 0; jj < 2; ++jj) {
                int col = h * 128 + wn * 32 + jj * 16 + l16;
                float bb = b2[col], ww = W3[col];
#pragma unroll
                for (int i = 0; i < 2; ++i)
#pragma unroll
                    for (int r = 0; r < 4; ++r)
                        s[i][r] = fmaf(fmaxf(acc[i][jj][r] + bb, 0.f), ww, s[i][r]);
            }
        }
    }
    if (w < 8) {
#pragma unroll
        for (int off = 1; off < 16; off <<= 1)
#pragma unroll
            for (int i = 0; i < 2; ++i)
#pragma unroll
                for (int r = 0; r < 4; ++r)
                    s[i][r] += __shfl_xor(s[i][r], off);
        if (l16 == 0)
#pragma unroll
            for (int i = 0; i < 2; ++i)
#pragma unroll
                for (int r = 0; r < 4; ++r)
                    part[wm * 32 + i * 16 + q * 4 + r][wn] = s[i][r];
    }
    __syncthreads();
    if (t < 64) {
        int node = r0 + t;
        if (node < M) {
            float v = part[t][0] + part[t][1] + part[t][2] + part[t][3] + b3[0];
            out[node] = 1.0f / (1.0f + expf(-v));
        }
    }
}

extern "C" void kernel_launch(void* const* d_in, const int* in_sizes, int n_in,
                              void* d_out, int out_size, void* d_ws, size_t ws_size,
                              hipStream_t stream) {
    const float* x      = (const float*)d_in[0];
    const int*   ei     = (const int*)d_in[1];   // [2, E]: src row then dst row
    const float* W_rel  = (const float*)d_in[2];
    const float* b_rel  = (const float*)d_in[3];
    const float* W_root = (const float*)d_in[4];
    const float* W1     = (const float*)d_in[5];
    const float* b1     = (const float*)d_in[6];
    const float* W2     = (const float*)d_in[7];
    const float* b2     = (const float*)d_in[8];
    const float* W3     = (const float*)d_in[9];
    const float* b3     = (const float*)d_in[10];
    float* out = (float*)d_out;
    const int E = in_sizes[1] / 2;

    char* p = (char*)d_ws;
    auto carve = [&](size_t bytes) { char* r = p; p += (bytes + 63) & ~size_t(63); return r; };
    u16* x_bf   = (u16*)carve((size_t)N_NODES * D_IN * 2);   // dense bf16 x
    u16* Wcat   = (u16*)carve(128 * 256 * 2);
    u16* W1b    = (u16*)carve(256 * 128 * 2);
    u16* W2b    = (u16*)carve(256 * 256 * 2);
    int* gcnt    = (int*)carve(NB * 4);
    int* buckets = (int*)carve((size_t)NB * BCAP * 4);       // 3.85 MB

    hipMemsetAsync(gcnt, 0, NB * sizeof(int), stream);
    prep_binsort<<<K1_GRID, 256, 0, stream>>>(
        x, ei, W_rel, W_root, W1, W2, x_bf, Wcat, W1b, W2b, gcnt, buckets, E);
    sortgather_mlp<<<K2_GRID, K2_THREADS, 0, stream>>>(
        gcnt, buckets, x_bf, Wcat, W1b, W2b, b_rel, b1, b2, W3, b3, out, N_NODES);
}

// Round 6
// 125.181 us; speedup vs baseline: 1.9209x; 1.0037x over previous
//
#include <hip/hip_runtime.h>
#include <hip/hip_bf16.h>
#include <cmath>

constexpr int N_NODES = 10000;
constexpr int D_IN = 128;   // GraphConv dim
constexpr int H_DIM = 256;  // MLP hidden

// Bucket geometry: bucket = dst>>5 (32 nodes/bucket), 313 buckets.
constexpr int NB = 313;
constexpr int BCAP = 3072;      // avg 2045 edges/bucket, sigma ~45 -> 22-sigma margin
constexpr int EPB_A = 2048;     // edges per K1 block (256 thr x 8)
constexpr int K1_GRID = 313;    // 313*2048 = 640k >= E
constexpr int K2_GRID = 157;    // (N_NODES+63)/64, 64 nodes (2 buckets) per block
constexpr int K2_THREADS = 1024;

typedef unsigned short u16;
typedef short bf16x8 __attribute__((ext_vector_type(8)));  // 8 bf16 = 4 VGPRs
typedef float f32x4 __attribute__((ext_vector_type(4)));

__device__ inline u16 f2bf(float f) {
    return __builtin_bit_cast(u16, __float2bfloat16(f));  // RNE hw cvt
}
__device__ inline float bf2f(u16 u) {
    unsigned int v = (unsigned int)u << 16;
    return __builtin_bit_cast(float, v);
}

// ===========================================================================
// K1: prep + binsort fused. 313 blocks x 256 thr.
//  - grid-strided x fp32->bf16 cast (320000 float4 chunks / 80128 threads)
//  - weight casts: Wcat=[W_rel|W_root] 128x256, W1b 256x128, W2b 256x256
//  - binsort slice: 2048 edges/block, LDS hist + one global cursor
//    reservation per (block,bucket) -> contiguous write runs.
// packed = (dst & 31) << 16 | src  (src < 65536). gcnt pre-zeroed by memset.
// ===========================================================================
__global__ __launch_bounds__(256)
void prep_binsort(const float* __restrict__ x, const int* __restrict__ ei,
                  const float* __restrict__ W_rel, const float* __restrict__ W_root,
                  const float* __restrict__ W1, const float* __restrict__ W2,
                  u16* __restrict__ x_bf, u16* __restrict__ Wcat,
                  u16* __restrict__ W1b, u16* __restrict__ W2b,
                  int* __restrict__ gcnt, int* __restrict__ buckets, int E)
{
    __shared__ int lcnt[NB], gbase[NB];
    const int t = threadIdx.x, blk = blockIdx.x;
    const int tid = blk * 256 + t;

    for (int i = t; i < NB; i += 256) lcnt[i] = 0;

    // x cast (streaming, overlaps with binsort's LDS work below)
    for (int idx = tid; idx < N_NODES * 32; idx += K1_GRID * 256) {
        int row = idx >> 5, c = (idx & 31) * 4;
        float4 v = *reinterpret_cast<const float4*>(x + (size_t)row * D_IN + c);
        ushort4 o;
        o.x = f2bf(v.x); o.y = f2bf(v.y); o.z = f2bf(v.z); o.w = f2bf(v.w);
        *reinterpret_cast<ushort4*>(x_bf + (size_t)row * D_IN + c) = o;
    }
    // weight casts (32768 float4 chunks; threads 0..32767)
    if (tid < 32768) {
        int idx4 = tid * 4;
        const float* src;
        u16* dst;
        if (idx4 < 32768) {            // Wcat = [W_rel|W_root]
            int n = idx4 >> 8, k = idx4 & 255;
            src = (k < 128) ? W_rel + n * 128 + k : W_root + n * 128 + (k - 128);
            dst = Wcat + idx4;
        } else if (idx4 < 65536) {     // W1
            src = W1 + (idx4 - 32768);
            dst = W1b + (idx4 - 32768);
        } else {                       // W2
            src = W2 + (idx4 - 65536);
            dst = W2b + (idx4 - 65536);
        }
        float4 v = *reinterpret_cast<const float4*>(src);
        ushort4 o;
        o.x = f2bf(v.x); o.y = f2bf(v.y); o.z = f2bf(v.z); o.w = f2bf(v.w);
        *reinterpret_cast<ushort4*>(dst) = o;
    }
    __syncthreads();

    // binsort slice (verbatim binsort_a body)
    const int e0 = blk * EPB_A + t;
    int packed[8], lpos[8], bb[8];
#pragma unroll
    for (int j = 0; j < 8; ++j) {
        int e = e0 + j * 256;
        if (e < E) {
            int s = ei[e], d = ei[E + e];
            int b = d >> 5;
            bb[j] = b;
            packed[j] = ((d & 31) << 16) | s;
            lpos[j] = atomicAdd(&lcnt[b], 1);
        } else bb[j] = -1;
    }
    __syncthreads();
    for (int i = t; i < NB; i += 256)
        gbase[i] = atomicAdd(&gcnt[i], lcnt[i]);
    __syncthreads();
#pragma unroll
    for (int j = 0; j < 8; ++j)
        if (bb[j] >= 0)
            buckets[bb[j] * BCAP + gbase[bb[j]] + lpos[j]] = packed[j];
}

// ===========================================================================
// K2: sort + gather + fused MLP. 157 blocks x 1024 thr (16 waves/CU, 2x the
// mega experiment's occupancy for the latency-bound gather). Block b owns
// buckets 2b,2b+1 = nodes 64b..64b+63.
//  - LDS counting-sort of both buckets (hist -> scan -> scatter)
//  - gather straight into the MFMA A-tile (bufA cols 0..127); x rows into
//    cols 128..255 (no agg_bf global round-trip)
//  - validated 3-phase MFMA MLP + head on waves 0..7 (tiling unchanged)
// LDS 122.6 KB -> 1 block/CU; 16 waves = 4/SIMD during gather.
// ===========================================================================
__global__ __launch_bounds__(K2_THREADS)
void sortgather_mlp(const int* __restrict__ gcnt, const int* __restrict__ buckets,
                    const u16* __restrict__ x_bf,
                    const u16* __restrict__ Wcat, const u16* __restrict__ W1b,
                    const u16* __restrict__ W2b,
                    const float* __restrict__ b_rel, const float* __restrict__ b1,
                    const float* __restrict__ b2, const float* __restrict__ W3,
                    const float* __restrict__ b3, float* __restrict__ out, int M)
{
    __shared__ alignas(16) u16 bufA[64 * 264];   // 33.8 KB: [agg|x], later h1
    __shared__ alignas(16) u16 bufH0[64 * 136];  // 17.4 KB
    union alignas(16) Ovl {
        struct { int edges[2][BCAP]; u16 ssrc[2][BCAP]; } s;  // sort scratch 36.9 KB
        u16 wbuf[34816];                                      // weight tiles 69.6 KB
    };
    __shared__ Ovl ovl;
    __shared__ int deg[2][32], cur[2][32], sbeg[2][32];
    __shared__ float part[64][4];

    const int t = threadIdx.x, blk = blockIdx.x;
    const int w = t >> 6, lane = t & 63;          // w in 0..15
    const int wm = (w >> 2) & 1, wn = w & 3;      // MFMA tiling (waves 0..7)
    const int l16 = lane & 15, q = lane >> 4;
    const int r0 = blk * 64;

    int cnt[2];
#pragma unroll
    for (int k = 0; k < 2; ++k) {
        int bk = blk * 2 + k;
        int c = (bk < NB) ? gcnt[bk] : 0;   // block 156's 2nd bucket: none
        cnt[k] = c > BCAP ? BCAP : c;
    }
    if (t < 64) deg[t >> 5][t & 31] = 0;
    __syncthreads();

    // stage self x rows -> bufA cols 128..255 (1024 chunks / 1024 thr)
    for (int idx = t; idx < 64 * 16; idx += K2_THREADS) {
        int row = idx >> 4, kc = (idx & 15) * 8;
        int gr = r0 + row; if (gr >= M) gr = M - 1;
        bf16x8 vx = *reinterpret_cast<const bf16x8*>(x_bf + (size_t)gr * D_IN + kc);
        *reinterpret_cast<bf16x8*>(&bufA[row * 264 + 128 + kc]) = vx;
    }
    // load bucket edges + per-node hist
#pragma unroll
    for (int k = 0; k < 2; ++k) {
        int bk = blk * 2 + k;
        for (int i = t; i < cnt[k]; i += K2_THREADS) {
            int p = buckets[bk * BCAP + i];
            ovl.s.edges[k][i] = p;
            atomicAdd(&deg[k][p >> 16], 1);
        }
    }
    __syncthreads();
    if (t < 64) {   // two 32-wide exclusive scans (width-32 shfl segments)
        int k = t >> 5, tl = t & 31;
        int d = deg[k][tl], incl = d;
#pragma unroll
        for (int off = 1; off < 32; off <<= 1) {
            int o = __shfl_up(incl, off, 32);
            if (tl >= off) incl += o;
        }
        cur[k][tl] = incl - d;
        sbeg[k][tl] = incl - d;
    }
    __syncthreads();
#pragma unroll
    for (int k = 0; k < 2; ++k)
        for (int i = t; i < cnt[k]; i += K2_THREADS) {
            int p = ovl.s.edges[k][i];
            int pos = atomicAdd(&cur[k][p >> 16], 1);
            ovl.s.ssrc[k][pos] = (u16)(p & 0xffff);
        }
    __syncthreads();

    // gather: wave w (of 16) -> nodes w*4..w*4+3 of the 64; half-wave per
    // node-half, ILP x4; agg -> bufA cols 0..127
    {
        const int c4 = (lane & 31) * 4;
        const int rh = lane >> 5;
#pragma unroll
        for (int j = 0; j < 4; ++j) {
            int ln = w * 4 + j;                 // 0..63
            int k = ln >> 5, lnn = ln & 31;
            const u16* sp = ovl.s.ssrc[k];
            int beg = sbeg[k][lnn], dg = deg[k][lnn];
            int half = (dg + 1) >> 1;
            int i = beg + (rh ? half : 0);
            const int i1 = rh ? beg + dg : beg + half;
            float4 a0 = {0, 0, 0, 0}, a1 = {0, 0, 0, 0};
            float4 a2 = {0, 0, 0, 0}, a3 = {0, 0, 0, 0};
            for (; i + 4 <= i1; i += 4) {
                int s0 = sp[i + 0], s1 = sp[i + 1];
                int s2 = sp[i + 2], s3 = sp[i + 3];
                ushort4 v0 = *reinterpret_cast<const ushort4*>(x_bf + (size_t)s0 * D_IN + c4);
                ushort4 v1 = *reinterpret_cast<const ushort4*>(x_bf + (size_t)s1 * D_IN + c4);
                ushort4 v2 = *reinterpret_cast<const ushort4*>(x_bf + (size_t)s2 * D_IN + c4);
                ushort4 v3 = *reinterpret_cast<const ushort4*>(x_bf + (size_t)s3 * D_IN + c4);
                a0.x += bf2f(v0.x); a0.y += bf2f(v0.y); a0.z += bf2f(v0.z); a0.w += bf2f(v0.w);
                a1.x += bf2f(v1.x); a1.y += bf2f(v1.y); a1.z += bf2f(v1.z); a1.w += bf2f(v1.w);
                a2.x += bf2f(v2.x); a2.y += bf2f(v2.y); a2.z += bf2f(v2.z); a2.w += bf2f(v2.w);
                a3.x += bf2f(v3.x); a3.y += bf2f(v3.y); a3.z += bf2f(v3.z); a3.w += bf2f(v3.w);
            }
            for (; i < i1; ++i) {
                int s = sp[i];
                ushort4 v = *reinterpret_cast<const ushort4*>(x_bf + (size_t)s * D_IN + c4);
                a0.x += bf2f(v.x); a0.y += bf2f(v.y); a0.z += bf2f(v.z); a0.w += bf2f(v.w);
            }
            a0.x += a1.x + a2.x + a3.x;
            a0.y += a1.y + a2.y + a3.y;
            a0.z += a1.z + a2.z + a3.z;
            a0.w += a1.w + a2.w + a3.w;
            a0.x += __shfl_xor(a0.x, 32);
            a0.y += __shfl_xor(a0.y, 32);
            a0.z += __shfl_xor(a0.z, 32);
            a0.w += __shfl_xor(a0.w, 32);
            if (rh == 0) {
                ushort4 o;
                o.x = f2bf(a0.x); o.y = f2bf(a0.y); o.z = f2bf(a0.z); o.w = f2bf(a0.w);
                *reinterpret_cast<ushort4*>(&bufA[ln * 264 + c4]) = o;
            }
        }
    }
    __syncthreads();   // sort scratch dead; bufA agg half complete

    // stage Wcat -> wbuf (overlays sort scratch)
    for (int idx = t; idx < 128 * 32; idx += K2_THREADS) {
        int row = idx >> 5, kc = (idx & 31) * 8;
        bf16x8 v = *reinterpret_cast<const bf16x8*>(Wcat + (size_t)row * 256 + kc);
        *reinterpret_cast<bf16x8*>(&ovl.wbuf[row * 264 + kc]) = v;
    }
    __syncthreads();

    // Phase 1: h0[64][128] = A @ Wcat^T + b_rel   (waves 0..7)
    if (w < 8) {
        f32x4 acc[2][2] = {};
#pragma unroll
        for (int k0 = 0; k0 < 256; k0 += 32) {
            bf16x8 af[2];
#pragma unroll
            for (int i = 0; i < 2; ++i)
                af[i] = *reinterpret_cast<const bf16x8*>(
                    &bufA[(wm * 32 + i * 16 + l16) * 264 + k0 + q * 8]);
#pragma unroll
            for (int jj = 0; jj < 2; ++jj) {
                int col = wn * 32 + jj * 16 + l16;
                bf16x8 bv = *reinterpret_cast<const bf16x8*>(
                    &ovl.wbuf[col * 264 + k0 + q * 8]);
                acc[0][jj] = __builtin_amdgcn_mfma_f32_16x16x32_bf16(af[0], bv, acc[0][jj], 0, 0, 0);
                acc[1][jj] = __builtin_amdgcn_mfma_f32_16x16x32_bf16(af[1], bv, acc[1][jj], 0, 0, 0);
            }
        }
#pragma unroll
        for (int i = 0; i < 2; ++i)
#pragma unroll
            for (int jj = 0; jj < 2; ++jj) {
                int col = wn * 32 + jj * 16 + l16;
                float bb = b_rel[col];
#pragma unroll
                for (int r = 0; r < 4; ++r) {
                    int row = wm * 32 + i * 16 + q * 4 + r;
                    bufH0[row * 136 + col] = f2bf(acc[i][jj][r] + bb);
                }
            }
    }
    __syncthreads();   // wbuf reads + bufH0 writes complete

    // Stage W1b [256][128] (stride 136).
    for (int idx = t; idx < 256 * 16; idx += K2_THREADS) {
        int row = idx >> 4, kc = (idx & 15) * 8;
        bf16x8 v = *reinterpret_cast<const bf16x8*>(W1b + (size_t)row * 128 + kc);
        *reinterpret_cast<bf16x8*>(&ovl.wbuf[row * 136 + kc]) = v;
    }
    __syncthreads();

    // Phase 2: h1[64][256] = relu(h0 @ W1^T + b1); h1 overlays bufA
    if (w < 8) {
        f32x4 acc[2][4] = {};
#pragma unroll
        for (int k0 = 0; k0 < 128; k0 += 32) {
            bf16x8 af[2];
#pragma unroll
            for (int i = 0; i < 2; ++i)
                af[i] = *reinterpret_cast<const bf16x8*>(
                    &bufH0[(wm * 32 + i * 16 + l16) * 136 + k0 + q * 8]);
#pragma unroll
            for (int jj = 0; jj < 4; ++jj) {
                int col = wn * 64 + jj * 16 + l16;
                bf16x8 bv = *reinterpret_cast<const bf16x8*>(
                    &ovl.wbuf[col * 136 + k0 + q * 8]);
                acc[0][jj] = __builtin_amdgcn_mfma_f32_16x16x32_bf16(af[0], bv, acc[0][jj], 0, 0, 0);
                acc[1][jj] = __builtin_amdgcn_mfma_f32_16x16x32_bf16(af[1], bv, acc[1][jj], 0, 0, 0);
            }
        }
#pragma unroll
        for (int i = 0; i < 2; ++i)
#pragma unroll
            for (int jj = 0; jj < 4; ++jj) {
                int col = wn * 64 + jj * 16 + l16;
                float bb = b1[col];
#pragma unroll
                for (int r = 0; r < 4; ++r) {
                    int row = wm * 32 + i * 16 + q * 4 + r;
                    bufA[row * 264 + col] = f2bf(fmaxf(acc[i][jj][r] + bb, 0.f));
                }
            }
    }

    // Phase 3 + head, in two 128-col halves of W2.
    float s[2][4] = {};
#pragma unroll
    for (int h = 0; h < 2; ++h) {
        __syncthreads();   // previous wbuf readers done (and h1 writes done)
        for (int idx = t; idx < 128 * 32; idx += K2_THREADS) {
            int row = idx >> 5, kc = (idx & 31) * 8;
            bf16x8 v = *reinterpret_cast<const bf16x8*>(
                W2b + (size_t)(h * 128 + row) * 256 + kc);
            *reinterpret_cast<bf16x8*>(&ovl.wbuf[row * 264 + kc]) = v;
        }
        __syncthreads();
        if (w < 8) {
            f32x4 acc[2][2] = {};
#pragma unroll
            for (int k0 = 0; k0 < 256; k0 += 32) {
                bf16x8 af[2];
#pragma unroll
                for (int i = 0; i < 2; ++i)
                    af[i] = *reinterpret_cast<const bf16x8*>(
                        &bufA[(wm * 32 + i * 16 + l16) * 264 + k0 + q * 8]);
#pragma unroll
                for (int jj = 0; jj < 2; ++jj) {
                    int lcol = wn * 32 + jj * 16 + l16;
                    bf16x8 bv = *reinterpret_cast<const bf16x8*>(
                        &ovl.wbuf[lcol * 264 + k0 + q * 8]);
                    acc[0][jj] = __builtin_amdgcn_mfma_f32_16x16x32_bf16(af[0], bv, acc[0][jj], 0, 0, 0);
                    acc[1][jj] = __builtin_amdgcn_mfma_f32_16x16x32_bf16(af[1], bv, acc[1][jj], 0, 0, 0);
                }
            }
#pragma unroll
            for (int jj = 0; jj < 2; ++jj) {
                int col = h * 128 + wn * 32 + jj * 16 + l16;
                float bb = b2[col], ww = W3[col];
#pragma unroll
                for (int i = 0; i < 2; ++i)
#pragma unroll
                    for (int r = 0; r < 4; ++r)
                        s[i][r] = fmaf(fmaxf(acc[i][jj][r] + bb, 0.f), ww, s[i][r]);
            }
        }
    }
    if (w < 8) {
#pragma unroll
        for (int off = 1; off < 16; off <<= 1)
#pragma unroll
            for (int i = 0; i < 2; ++i)
#pragma unroll
                for (int r = 0; r < 4; ++r)
                    s[i][r] += __shfl_xor(s[i][r], off);
        if (l16 == 0)
#pragma unroll
            for (int i = 0; i < 2; ++i)
#pragma unroll
                for (int r = 0; r < 4; ++r)
                    part[wm * 32 + i * 16 + q * 4 + r][wn] = s[i][r];
    }
    __syncthreads();
    if (t < 64) {
        int node = r0 + t;
        if (node < M) {
            float v = part[t][0] + part[t][1] + part[t][2] + part[t][3] + b3[0];
            out[node] = 1.0f / (1.0f + expf(-v));
        }
    }
}

extern "C" void kernel_launch(void* const* d_in, const int* in_sizes, int n_in,
                              void* d_out, int out_size, void* d_ws, size_t ws_size,
                              hipStream_t stream) {
    const float* x      = (const float*)d_in[0];
    const int*   ei     = (const int*)d_in[1];   // [2, E]: src row then dst row
    const float* W_rel  = (const float*)d_in[2];
    const float* b_rel  = (const float*)d_in[3];
    const float* W_root = (const float*)d_in[4];
    const float* W1     = (const float*)d_in[5];
    const float* b1     = (const float*)d_in[6];
    const float* W2     = (const float*)d_in[7];
    const float* b2     = (const float*)d_in[8];
    const float* W3     = (const float*)d_in[9];
    const float* b3     = (const float*)d_in[10];
    float* out = (float*)d_out;
    const int E = in_sizes[1] / 2;

    char* p = (char*)d_ws;
    auto carve = [&](size_t bytes) { char* r = p; p += (bytes + 63) & ~size_t(63); return r; };
    u16* x_bf   = (u16*)carve((size_t)N_NODES * D_IN * 2);   // dense bf16 x
    u16* Wcat   = (u16*)carve(128 * 256 * 2);
    u16* W1b    = (u16*)carve(256 * 128 * 2);
    u16* W2b    = (u16*)carve(256 * 256 * 2);
    int* gcnt    = (int*)carve(NB * 4);
    int* buckets = (int*)carve((size_t)NB * BCAP * 4);       // 3.85 MB

    hipMemsetAsync(gcnt, 0, NB * sizeof(int), stream);
    prep_binsort<<<K1_GRID, 256, 0, stream>>>(
        x, ei, W_rel, W_root, W1, W2, x_bf, Wcat, W1b, W2b, gcnt, buckets, E);
    sortgather_mlp<<<K2_GRID, K2_THREADS, 0, stream>>>(
        gcnt, buckets, x_bf, Wcat, W1b, W2b, b_rel, b1, b2, W3, b3, out, N_NODES);
}